// Round 8
// baseline (146.826 us; speedup 1.0000x reference)
//
#include <hip/hip_runtime.h>

typedef float f32x4 __attribute__((ext_vector_type(4)));

#define BF_DIM 1024
#define BF_STAGES 10

// Tables: cs[s*512 + pos] = (cos, sin) of angles[s][k].
// Stages 0-3, 8, 9: pos = k (natural).
// Stages 4-7: permuted so each lane's 8 needed entries are contiguous:
//   k = hi2*128 + j*16 + lo4  ->  pos = (hi2*16 + lo4)*8 + j
__global__ void bf_fill_cs(const float* __restrict__ angles, float2* __restrict__ cs, int n) {
    int i = blockIdx.x * blockDim.x + threadIdx.x;
    if (i >= n) return;
    int s = i >> 9, k = i & 511;
    float a = angles[i];
    float sv, cv;
    sincosf(a, &sv, &cv);
    int pos;
    if (s >= 4 && s < 8) {
        int hi2 = k >> 7, j = (k >> 4) & 7, lo4 = k & 15;
        pos = ((hi2 << 4) | lo4) * 8 + j;
    } else {
        pos = k;
    }
    cs[s * 512 + pos] = make_float2(cv, sv);
}

#define ROT(vi, vj, c, s) do { float _t = fmaf(-(s), (vj), (c)*(vi)); \
                               (vj) = fmaf((s), (vi), (c)*(vj)); (vi) = _t; } while (0)

#define STAGE_EVEN_INNER(A0,A1,A2,A3,c0,c1,c2,c3) do { \
    ROT(A0.x,A0.y,c0.x,c0.y); ROT(A0.z,A0.w,c0.z,c0.w); \
    ROT(A1.x,A1.y,c1.x,c1.y); ROT(A1.z,A1.w,c1.z,c1.w); \
    ROT(A2.x,A2.y,c2.x,c2.y); ROT(A2.z,A2.w,c2.z,c2.w); \
    ROT(A3.x,A3.y,c3.x,c3.y); ROT(A3.z,A3.w,c3.z,c3.w); } while (0)
#define STAGE_ODD_INNER(A0,A1,A2,A3,c0,c1,c2,c3) do { \
    ROT(A0.x,A0.z,c0.x,c0.y); ROT(A0.y,A0.w,c0.z,c0.w); \
    ROT(A1.x,A1.z,c1.x,c1.y); ROT(A1.y,A1.w,c1.z,c1.w); \
    ROT(A2.x,A2.z,c2.x,c2.y); ROT(A2.y,A2.w,c2.z,c2.w); \
    ROT(A3.x,A3.z,c3.x,c3.y); ROT(A3.y,A3.w,c3.z,c3.w); } while (0)
#define STAGE_PAIR01(A0,A1,A2,A3,c0,c1,c2,c3) do { \
    ROT(A0.x,A1.x,c0.x,c0.y); ROT(A0.y,A1.y,c0.z,c0.w); \
    ROT(A0.z,A1.z,c1.x,c1.y); ROT(A0.w,A1.w,c1.z,c1.w); \
    ROT(A2.x,A3.x,c2.x,c2.y); ROT(A2.y,A3.y,c2.z,c2.w); \
    ROT(A2.z,A3.z,c3.x,c3.y); ROT(A2.w,A3.w,c3.z,c3.w); } while (0)
#define STAGE_PAIR02(A0,A1,A2,A3,c0,c1,c2,c3) do { \
    ROT(A0.x,A2.x,c0.x,c0.y); ROT(A0.y,A2.y,c0.z,c0.w); \
    ROT(A0.z,A2.z,c1.x,c1.y); ROT(A0.w,A2.w,c1.z,c1.w); \
    ROT(A1.x,A3.x,c2.x,c2.y); ROT(A1.y,A3.y,c2.z,c2.w); \
    ROT(A1.z,A3.z,c3.x,c3.y); ROT(A1.w,A3.w,c3.z,c3.w); } while (0)

// One wave = TWO rows/iteration (shared stage tables), 16 elems/thread/row,
// zero shuffles, ZERO barriers (wave-private slab; same-wave DS ops are
// pipe-ordered and alias-visible to the compiler, so program order suffices).
// Round-8 change: ONE slab per wave, stride-17 layout W(r,c) = r*17 + c:
//   slab 64*17 = 1088 words = 4352 B/wave -> 17408 B/block -> 8 blocks/CU
//   = 32 waves/CU = 8 waves/SIMD (2x round-7 TLP; latency-bound fix).
// Bank math at stride 17: b32 phases = (16*(l>>4) + 17j + (l&15)) mod 32 ->
// exactly 2-way (free on CDNA4); b128 phases spread over odd 17-multiples.
__global__ __launch_bounds__(256) void bf_butterfly(const float* __restrict__ x,
                                                    const f32x4* __restrict__ T,
                                                    float* __restrict__ out,
                                                    int n_rows, int pair_stride) {
    __shared__ __align__(16) float lds[4 * 1088];  // 4 waves * 1088 words = 17408 B
    const int lane = threadIdx.x & 63;
    const int wv   = threadIdx.x >> 6;
    float* L = lds + wv * 1088;

    const int ta = lane * 4;                          // table slice (f32x4 idx)
    const int wb = lane * 17;                         // layout A base
    const int rb = (lane >> 4) * 272 + (lane & 15);   // layout B base (+ j*17)
    const int cb = (lane >> 2) * 17 + (lane & 3) * 4; // layout C base (+ q*272)

    const int n_pairs = (n_rows + 1) >> 1;

#pragma unroll 1
    for (int pair = blockIdx.x * 4 + wv; pair < n_pairs; pair += pair_stride) {
        const int r0 = pair * 2;
        const int r1 = r0 + 1;
        const bool has1 = (r1 < n_rows);

        const float* xr0 = x + (long long)r0 * BF_DIM + lane * 16;
        const float* xr1 = x + (long long)(has1 ? r1 : r0) * BF_DIM + lane * 16;
        f32x4 U0 = __builtin_nontemporal_load((const f32x4*)(xr0 + 0));
        f32x4 U1 = __builtin_nontemporal_load((const f32x4*)(xr0 + 4));
        f32x4 U2 = __builtin_nontemporal_load((const f32x4*)(xr0 + 8));
        f32x4 U3 = __builtin_nontemporal_load((const f32x4*)(xr0 + 12));
        f32x4 W0 = __builtin_nontemporal_load((const f32x4*)(xr1 + 0));
        f32x4 W1 = __builtin_nontemporal_load((const f32x4*)(xr1 + 4));
        f32x4 W2 = __builtin_nontemporal_load((const f32x4*)(xr1 + 8));
        f32x4 W3 = __builtin_nontemporal_load((const f32x4*)(xr1 + 12));

        {   // stage 0 (tables shared by both rows)
            f32x4 c0 = T[ta], c1 = T[ta + 1], c2 = T[ta + 2], c3 = T[ta + 3];
            STAGE_EVEN_INNER(U0, U1, U2, U3, c0, c1, c2, c3);
            STAGE_EVEN_INNER(W0, W1, W2, W3, c0, c1, c2, c3);
        }
        {   // stage 1
            f32x4 c0 = T[256 + ta], c1 = T[256 + ta + 1], c2 = T[256 + ta + 2], c3 = T[256 + ta + 3];
            STAGE_ODD_INNER(U0, U1, U2, U3, c0, c1, c2, c3);
            STAGE_ODD_INNER(W0, W1, W2, W3, c0, c1, c2, c3);
        }
        {   // stage 2
            f32x4 c0 = T[512 + ta], c1 = T[512 + ta + 1], c2 = T[512 + ta + 2], c3 = T[512 + ta + 3];
            STAGE_PAIR01(U0, U1, U2, U3, c0, c1, c2, c3);
            STAGE_PAIR01(W0, W1, W2, W3, c0, c1, c2, c3);
        }
        {   // stage 3
            f32x4 c0 = T[768 + ta], c1 = T[768 + ta + 1], c2 = T[768 + ta + 2], c3 = T[768 + ta + 3];
            STAGE_PAIR02(U0, U1, U2, U3, c0, c1, c2, c3);
            STAGE_PAIR02(W0, W1, W2, W3, c0, c1, c2, c3);
        }

        // ---- transpose 1, row 0 then row 1 through the SAME slab.
        // readB(U) issues before writeA(W); same-wave DS pipe is in-order and
        // the accesses alias -> no barrier needed.
        *(f32x4*)(L + wb + 0)  = U0;
        *(f32x4*)(L + wb + 4)  = U1;
        *(f32x4*)(L + wb + 8)  = U2;
        *(f32x4*)(L + wb + 12) = U3;
        U0.x = L[rb + 0 * 17];  U0.y = L[rb + 1 * 17];  U0.z = L[rb + 2 * 17];  U0.w = L[rb + 3 * 17];
        U1.x = L[rb + 4 * 17];  U1.y = L[rb + 5 * 17];  U1.z = L[rb + 6 * 17];  U1.w = L[rb + 7 * 17];
        U2.x = L[rb + 8 * 17];  U2.y = L[rb + 9 * 17];  U2.z = L[rb + 10 * 17]; U2.w = L[rb + 11 * 17];
        U3.x = L[rb + 12 * 17]; U3.y = L[rb + 13 * 17]; U3.z = L[rb + 14 * 17]; U3.w = L[rb + 15 * 17];
        *(f32x4*)(L + wb + 0)  = W0;
        *(f32x4*)(L + wb + 4)  = W1;
        *(f32x4*)(L + wb + 8)  = W2;
        *(f32x4*)(L + wb + 12) = W3;
        W0.x = L[rb + 0 * 17];  W0.y = L[rb + 1 * 17];  W0.z = L[rb + 2 * 17];  W0.w = L[rb + 3 * 17];
        W1.x = L[rb + 4 * 17];  W1.y = L[rb + 5 * 17];  W1.z = L[rb + 6 * 17];  W1.w = L[rb + 7 * 17];
        W2.x = L[rb + 8 * 17];  W2.y = L[rb + 9 * 17];  W2.z = L[rb + 10 * 17]; W2.w = L[rb + 11 * 17];
        W3.x = L[rb + 12 * 17]; W3.y = L[rb + 13 * 17]; W3.z = L[rb + 14 * 17]; W3.w = L[rb + 15 * 17];

        {   // stage 4
            f32x4 c0 = T[1024 + ta], c1 = T[1024 + ta + 1], c2 = T[1024 + ta + 2], c3 = T[1024 + ta + 3];
            STAGE_EVEN_INNER(U0, U1, U2, U3, c0, c1, c2, c3);
            STAGE_EVEN_INNER(W0, W1, W2, W3, c0, c1, c2, c3);
        }
        {   // stage 5
            f32x4 c0 = T[1280 + ta], c1 = T[1280 + ta + 1], c2 = T[1280 + ta + 2], c3 = T[1280 + ta + 3];
            STAGE_ODD_INNER(U0, U1, U2, U3, c0, c1, c2, c3);
            STAGE_ODD_INNER(W0, W1, W2, W3, c0, c1, c2, c3);
        }
        {   // stage 6
            f32x4 c0 = T[1536 + ta], c1 = T[1536 + ta + 1], c2 = T[1536 + ta + 2], c3 = T[1536 + ta + 3];
            STAGE_PAIR01(U0, U1, U2, U3, c0, c1, c2, c3);
            STAGE_PAIR01(W0, W1, W2, W3, c0, c1, c2, c3);
        }
        {   // stage 7
            f32x4 c0 = T[1792 + ta], c1 = T[1792 + ta + 1], c2 = T[1792 + ta + 2], c3 = T[1792 + ta + 3];
            STAGE_PAIR02(U0, U1, U2, U3, c0, c1, c2, c3);
            STAGE_PAIR02(W0, W1, W2, W3, c0, c1, c2, c3);
        }

        // ---- transpose 2, row 0 then row 1 through the SAME slab.
        L[rb + 0 * 17]  = U0.x; L[rb + 1 * 17]  = U0.y; L[rb + 2 * 17]  = U0.z; L[rb + 3 * 17]  = U0.w;
        L[rb + 4 * 17]  = U1.x; L[rb + 5 * 17]  = U1.y; L[rb + 6 * 17]  = U1.z; L[rb + 7 * 17]  = U1.w;
        L[rb + 8 * 17]  = U2.x; L[rb + 9 * 17]  = U2.y; L[rb + 10 * 17] = U2.z; L[rb + 11 * 17] = U2.w;
        L[rb + 12 * 17] = U3.x; L[rb + 13 * 17] = U3.y; L[rb + 14 * 17] = U3.z; L[rb + 15 * 17] = U3.w;
        U0 = *(const f32x4*)(L + cb);
        U1 = *(const f32x4*)(L + cb + 272);
        U2 = *(const f32x4*)(L + cb + 544);
        U3 = *(const f32x4*)(L + cb + 816);
        L[rb + 0 * 17]  = W0.x; L[rb + 1 * 17]  = W0.y; L[rb + 2 * 17]  = W0.z; L[rb + 3 * 17]  = W0.w;
        L[rb + 4 * 17]  = W1.x; L[rb + 5 * 17]  = W1.y; L[rb + 6 * 17]  = W1.z; L[rb + 7 * 17]  = W1.w;
        L[rb + 8 * 17]  = W2.x; L[rb + 9 * 17]  = W2.y; L[rb + 10 * 17] = W2.z; L[rb + 11 * 17] = W2.w;
        L[rb + 12 * 17] = W3.x; L[rb + 13 * 17] = W3.y; L[rb + 14 * 17] = W3.z; L[rb + 15 * 17] = W3.w;
        W0 = *(const f32x4*)(L + cb);
        W1 = *(const f32x4*)(L + cb + 272);
        W2 = *(const f32x4*)(L + cb + 544);
        W3 = *(const f32x4*)(L + cb + 816);

        {   // stage 8: (0,1), (2,3)
            f32x4 t0 = T[2048 + lane * 2], t1 = T[2048 + lane * 2 + 1];
            f32x4 t2 = T[2048 + 128 + lane * 2], t3 = T[2048 + 128 + lane * 2 + 1];
            ROT(U0.x, U1.x, t0.x, t0.y); ROT(U0.y, U1.y, t0.z, t0.w);
            ROT(U0.z, U1.z, t1.x, t1.y); ROT(U0.w, U1.w, t1.z, t1.w);
            ROT(U2.x, U3.x, t2.x, t2.y); ROT(U2.y, U3.y, t2.z, t2.w);
            ROT(U2.z, U3.z, t3.x, t3.y); ROT(U2.w, U3.w, t3.z, t3.w);
            ROT(W0.x, W1.x, t0.x, t0.y); ROT(W0.y, W1.y, t0.z, t0.w);
            ROT(W0.z, W1.z, t1.x, t1.y); ROT(W0.w, W1.w, t1.z, t1.w);
            ROT(W2.x, W3.x, t2.x, t2.y); ROT(W2.y, W3.y, t2.z, t2.w);
            ROT(W2.z, W3.z, t3.x, t3.y); ROT(W2.w, W3.w, t3.z, t3.w);
        }
        {   // stage 9: (0,2), (1,3)
            f32x4 t0 = T[2304 + lane * 2], t1 = T[2304 + lane * 2 + 1];
            f32x4 t2 = T[2304 + 128 + lane * 2], t3 = T[2304 + 128 + lane * 2 + 1];
            ROT(U0.x, U2.x, t0.x, t0.y); ROT(U0.y, U2.y, t0.z, t0.w);
            ROT(U0.z, U2.z, t1.x, t1.y); ROT(U0.w, U2.w, t1.z, t1.w);
            ROT(U1.x, U3.x, t2.x, t2.y); ROT(U1.y, U3.y, t2.z, t2.w);
            ROT(U1.z, U3.z, t3.x, t3.y); ROT(U1.w, U3.w, t3.z, t3.w);
            ROT(W0.x, W2.x, t0.x, t0.y); ROT(W0.y, W2.y, t0.z, t0.w);
            ROT(W0.z, W2.z, t1.x, t1.y); ROT(W0.w, W2.w, t1.z, t1.w);
            ROT(W1.x, W3.x, t2.x, t2.y); ROT(W1.y, W3.y, t2.z, t2.w);
            ROT(W1.z, W3.z, t3.x, t3.y); ROT(W1.w, W3.w, t3.z, t3.w);
        }

        float* o0 = out + (long long)r0 * BF_DIM;
        __builtin_nontemporal_store(U0, (f32x4*)(o0 + lane * 4));
        __builtin_nontemporal_store(U1, (f32x4*)(o0 + 256 + lane * 4));
        __builtin_nontemporal_store(U2, (f32x4*)(o0 + 512 + lane * 4));
        __builtin_nontemporal_store(U3, (f32x4*)(o0 + 768 + lane * 4));
        if (has1) {
            float* o1 = out + (long long)r1 * BF_DIM;
            __builtin_nontemporal_store(W0, (f32x4*)(o1 + lane * 4));
            __builtin_nontemporal_store(W1, (f32x4*)(o1 + 256 + lane * 4));
            __builtin_nontemporal_store(W2, (f32x4*)(o1 + 512 + lane * 4));
            __builtin_nontemporal_store(W3, (f32x4*)(o1 + 768 + lane * 4));
        }
    }
}

extern "C" void kernel_launch(void* const* d_in, const int* in_sizes, int n_in,
                              void* d_out, int out_size, void* d_ws, size_t ws_size,
                              hipStream_t stream) {
    const float* x      = (const float*)d_in[0];
    const float* angles = (const float*)d_in[1];
    float*       out    = (float*)d_out;
    float2*      cs     = (float2*)d_ws;  // 10*512*8 = 40960 bytes

    const int ncs = BF_STAGES * (BF_DIM / 2);
    bf_fill_cs<<<(ncs + 255) / 256, 256, 0, stream>>>(angles, cs, ncs);

    const int rows    = in_sizes[0] / BF_DIM;
    const int n_pairs = (rows + 1) / 2;
    int blocks = (n_pairs + 3) / 4;
    if (blocks > 2048) blocks = 2048;     // 8 blocks/CU (17.4KB LDS each) resident
    const int pair_stride = blocks * 4;   // total waves
    bf_butterfly<<<blocks, 256, 0, stream>>>(x, (const f32x4*)cs, out, rows, pair_stride);
}

// Round 9
// 124.112 us; speedup vs baseline: 1.1830x; 1.1830x over previous
//
#include <hip/hip_runtime.h>
#include <hip/hip_fp16.h>

typedef float    f32x4 __attribute__((ext_vector_type(4)));
typedef _Float16 f16x8 __attribute__((ext_vector_type(8)));

#define BF_DIM 1024
#define BF_STAGES 10

// f16 (cos,sin) tables: 4 B/pair, 2 KB/stage, 20 KB total -> fully L1-resident.
// Per stage, lane l's 8 needed pairs are packed contiguously at pairs [l*8..l*8+7]:
//   stages 0-3: pos = k (natural order IS lane-contiguous for the reg layout)
//   stages 4-7: k = hi2*128 + j*16 + lo4 -> pos = (hi2*16+lo4)*8 + j   (layout B)
//   stages 8-9: k = g*256 + lane*4 + c   -> pos = lane*8 + g*4 + c     (layout C)
__global__ void bf_fill_cs(const float* __restrict__ angles, unsigned* __restrict__ cs, int n) {
    int i = blockIdx.x * blockDim.x + threadIdx.x;
    if (i >= n) return;
    int s = i >> 9, k = i & 511;
    float a = angles[i];
    float sv, cv;
    sincosf(a, &sv, &cv);
    int pos;
    if (s >= 4 && s < 8) {
        int hi2 = k >> 7, j = (k >> 4) & 7, lo4 = k & 15;
        pos = ((hi2 << 4) | lo4) * 8 + j;
    } else if (s >= 8) {
        pos = ((k & 255) >> 2) * 8 + (k >> 8) * 4 + (k & 3);
    } else {
        pos = k;
    }
    unsigned hc = __half_as_ushort(__float2half_rn(cv));
    unsigned hs = __half_as_ushort(__float2half_rn(sv));
    cs[s * 512 + pos] = (hs << 16) | hc;   // low16 = cos, high16 = sin (LE)
}

#define ROT(vi, vj, c, s) do { float _t = fmaf(-(s), (vj), (c)*(vi)); \
                               (vj) = fmaf((s), (vi), (c)*(vj)); (vi) = _t; } while (0)

// Expand one f16x8 (4 cos/sin pairs) into two f32x4 coeff vecs (c0,s0,c1,s1).
#define EXP(t, ca, cb) do { \
    ca = (f32x4){(float)(t)[0], (float)(t)[1], (float)(t)[2], (float)(t)[3]}; \
    cb = (f32x4){(float)(t)[4], (float)(t)[5], (float)(t)[6], (float)(t)[7]}; } while (0)

// Half-stage ops on a pair of data vecs with 2 coeff vecs (4 pairs).
#define H_EVEN(P, Q, c0, c1) do { \
    ROT(P.x, P.y, c0.x, c0.y); ROT(P.z, P.w, c0.z, c0.w); \
    ROT(Q.x, Q.y, c1.x, c1.y); ROT(Q.z, Q.w, c1.z, c1.w); } while (0)
#define H_ODD(P, Q, c0, c1) do { \
    ROT(P.x, P.z, c0.x, c0.y); ROT(P.y, P.w, c0.z, c0.w); \
    ROT(Q.x, Q.z, c1.x, c1.y); ROT(Q.y, Q.w, c1.z, c1.w); } while (0)
#define H_PAIR(P, Q, c0, c1) do { \
    ROT(P.x, Q.x, c0.x, c0.y); ROT(P.y, Q.y, c0.z, c0.w); \
    ROT(P.z, Q.z, c1.x, c1.y); ROT(P.w, Q.w, c1.z, c1.w); } while (0)

// One full stage = two f16x8 loads; expand lazily (t0 used on both rows, then
// t1 reuses the same coeff regs) to keep the live set under the 64-VGPR cap.
#define DO_STAGE(HOP, sidx, X0, X1, X2, X3, Y0, Y1, Y2, Y3) do { \
    f16x8 _t0 = TH[(sidx) * 128 + lane * 2], _t1 = TH[(sidx) * 128 + lane * 2 + 1]; \
    f32x4 _c0, _c1; \
    EXP(_t0, _c0, _c1); \
    HOP(X0, X1, _c0, _c1); HOP(Y0, Y1, _c0, _c1); \
    EXP(_t1, _c0, _c1); \
    HOP(X2, X3, _c0, _c1); HOP(Y2, Y3, _c0, _c1); } while (0)

// r7 structure (136us baseline): one wave = TWO rows/iteration, separate
// per-row transpose slabs (stride 20), zero barriers (wave-private slabs,
// same-wave DS ops pipe-ordered). Round-9 change: f16-packed L1-resident
// tables, one f16x8 load per half-stage (table VMEM insts 40 -> 20 per pair,
// L2-latency stalls -> L1 hits). Data keeps nt loads/stores so the 20 KB
// table is not evicted from L1 by the stream.
__global__ __launch_bounds__(256) void bf_butterfly(const float* __restrict__ x,
                                                    const f16x8* __restrict__ TH,
                                                    float* __restrict__ out,
                                                    int n_rows, int pair_stride) {
    __shared__ __align__(16) float lds[4 * 2560];  // 4 waves * 2 rows * 20*64 words = 40 KB
    const int lane = threadIdx.x & 63;
    const int wv   = threadIdx.x >> 6;
    float* LA = lds + wv * 2560;   // row 0 slab
    float* LB = LA + 1280;         // row 1 slab

    const int wb = lane * 20;                         // layout A base
    const int rb = (lane >> 4) * 320 + (lane & 15);   // layout B base
    const int cb = (lane >> 2) * 20 + (lane & 3) * 4; // layout C base

    const int n_pairs = (n_rows + 1) >> 1;

#pragma unroll 1
    for (int pair = blockIdx.x * 4 + wv; pair < n_pairs; pair += pair_stride) {
        const int r0 = pair * 2;
        const int r1 = r0 + 1;
        const bool has1 = (r1 < n_rows);

        const float* xr0 = x + (long long)r0 * BF_DIM + lane * 16;
        const float* xr1 = x + (long long)(has1 ? r1 : r0) * BF_DIM + lane * 16;
        f32x4 U0 = __builtin_nontemporal_load((const f32x4*)(xr0 + 0));
        f32x4 U1 = __builtin_nontemporal_load((const f32x4*)(xr0 + 4));
        f32x4 U2 = __builtin_nontemporal_load((const f32x4*)(xr0 + 8));
        f32x4 U3 = __builtin_nontemporal_load((const f32x4*)(xr0 + 12));
        f32x4 W0 = __builtin_nontemporal_load((const f32x4*)(xr1 + 0));
        f32x4 W1 = __builtin_nontemporal_load((const f32x4*)(xr1 + 4));
        f32x4 W2 = __builtin_nontemporal_load((const f32x4*)(xr1 + 8));
        f32x4 W3 = __builtin_nontemporal_load((const f32x4*)(xr1 + 12));

        // ---- stages 0-3 (layout A, in regs)
        DO_STAGE(H_EVEN, 0, U0, U1, U2, U3, W0, W1, W2, W3);
        DO_STAGE(H_ODD,  1, U0, U1, U2, U3, W0, W1, W2, W3);
        DO_STAGE(H_PAIR, 2, U0, U1, U2, U3, W0, W1, W2, W3);
        DO_STAGE(H_PAIR, 3, U0, U2, U1, U3, W0, W2, W1, W3);  // pairs (0,2),(1,3)

        // ---- transpose 1: write layout A (b128), read layout B (b32); wave-private
        *(f32x4*)(LA + wb + 0)  = U0;
        *(f32x4*)(LA + wb + 4)  = U1;
        *(f32x4*)(LA + wb + 8)  = U2;
        *(f32x4*)(LA + wb + 12) = U3;
        *(f32x4*)(LB + wb + 0)  = W0;
        *(f32x4*)(LB + wb + 4)  = W1;
        *(f32x4*)(LB + wb + 8)  = W2;
        *(f32x4*)(LB + wb + 12) = W3;
        U0.x = LA[rb + 0 * 20];  U0.y = LA[rb + 1 * 20];  U0.z = LA[rb + 2 * 20];  U0.w = LA[rb + 3 * 20];
        U1.x = LA[rb + 4 * 20];  U1.y = LA[rb + 5 * 20];  U1.z = LA[rb + 6 * 20];  U1.w = LA[rb + 7 * 20];
        U2.x = LA[rb + 8 * 20];  U2.y = LA[rb + 9 * 20];  U2.z = LA[rb + 10 * 20]; U2.w = LA[rb + 11 * 20];
        U3.x = LA[rb + 12 * 20]; U3.y = LA[rb + 13 * 20]; U3.z = LA[rb + 14 * 20]; U3.w = LA[rb + 15 * 20];
        W0.x = LB[rb + 0 * 20];  W0.y = LB[rb + 1 * 20];  W0.z = LB[rb + 2 * 20];  W0.w = LB[rb + 3 * 20];
        W1.x = LB[rb + 4 * 20];  W1.y = LB[rb + 5 * 20];  W1.z = LB[rb + 6 * 20];  W1.w = LB[rb + 7 * 20];
        W2.x = LB[rb + 8 * 20];  W2.y = LB[rb + 9 * 20];  W2.z = LB[rb + 10 * 20]; W2.w = LB[rb + 11 * 20];
        W3.x = LB[rb + 12 * 20]; W3.y = LB[rb + 13 * 20]; W3.z = LB[rb + 14 * 20]; W3.w = LB[rb + 15 * 20];

        // ---- stages 4-7 (layout B, in regs)
        DO_STAGE(H_EVEN, 4, U0, U1, U2, U3, W0, W1, W2, W3);
        DO_STAGE(H_ODD,  5, U0, U1, U2, U3, W0, W1, W2, W3);
        DO_STAGE(H_PAIR, 6, U0, U1, U2, U3, W0, W1, W2, W3);
        DO_STAGE(H_PAIR, 7, U0, U2, U1, U3, W0, W2, W1, W3);

        // ---- transpose 2: write layout B back (b32), read layout C (b128)
        LA[rb + 0 * 20]  = U0.x; LA[rb + 1 * 20]  = U0.y; LA[rb + 2 * 20]  = U0.z; LA[rb + 3 * 20]  = U0.w;
        LA[rb + 4 * 20]  = U1.x; LA[rb + 5 * 20]  = U1.y; LA[rb + 6 * 20]  = U1.z; LA[rb + 7 * 20]  = U1.w;
        LA[rb + 8 * 20]  = U2.x; LA[rb + 9 * 20]  = U2.y; LA[rb + 10 * 20] = U2.z; LA[rb + 11 * 20] = U2.w;
        LA[rb + 12 * 20] = U3.x; LA[rb + 13 * 20] = U3.y; LA[rb + 14 * 20] = U3.z; LA[rb + 15 * 20] = U3.w;
        LB[rb + 0 * 20]  = W0.x; LB[rb + 1 * 20]  = W0.y; LB[rb + 2 * 20]  = W0.z; LB[rb + 3 * 20]  = W0.w;
        LB[rb + 4 * 20]  = W1.x; LB[rb + 5 * 20]  = W1.y; LB[rb + 6 * 20]  = W1.z; LB[rb + 7 * 20]  = W1.w;
        LB[rb + 8 * 20]  = W2.x; LB[rb + 9 * 20]  = W2.y; LB[rb + 10 * 20] = W2.z; LB[rb + 11 * 20] = W2.w;
        LB[rb + 12 * 20] = W3.x; LB[rb + 13 * 20] = W3.y; LB[rb + 14 * 20] = W3.z; LB[rb + 15 * 20] = W3.w;
        U0 = *(const f32x4*)(LA + cb);
        U1 = *(const f32x4*)(LA + cb + 320);
        U2 = *(const f32x4*)(LA + cb + 640);
        U3 = *(const f32x4*)(LA + cb + 960);
        W0 = *(const f32x4*)(LB + cb);
        W1 = *(const f32x4*)(LB + cb + 320);
        W2 = *(const f32x4*)(LB + cb + 640);
        W3 = *(const f32x4*)(LB + cb + 960);

        // ---- stages 8-9 (layout C, in regs): (V0,V1),(V2,V3) then (V0,V2),(V1,V3)
        DO_STAGE(H_PAIR, 8, U0, U1, U2, U3, W0, W1, W2, W3);
        DO_STAGE(H_PAIR, 9, U0, U2, U1, U3, W0, W2, W1, W3);

        float* o0 = out + (long long)r0 * BF_DIM;
        __builtin_nontemporal_store(U0, (f32x4*)(o0 + lane * 4));
        __builtin_nontemporal_store(U1, (f32x4*)(o0 + 256 + lane * 4));
        __builtin_nontemporal_store(U2, (f32x4*)(o0 + 512 + lane * 4));
        __builtin_nontemporal_store(U3, (f32x4*)(o0 + 768 + lane * 4));
        if (has1) {
            float* o1 = out + (long long)r1 * BF_DIM;
            __builtin_nontemporal_store(W0, (f32x4*)(o1 + lane * 4));
            __builtin_nontemporal_store(W1, (f32x4*)(o1 + 256 + lane * 4));
            __builtin_nontemporal_store(W2, (f32x4*)(o1 + 512 + lane * 4));
            __builtin_nontemporal_store(W3, (f32x4*)(o1 + 768 + lane * 4));
        }
    }
}

extern "C" void kernel_launch(void* const* d_in, const int* in_sizes, int n_in,
                              void* d_out, int out_size, void* d_ws, size_t ws_size,
                              hipStream_t stream) {
    const float* x      = (const float*)d_in[0];
    const float* angles = (const float*)d_in[1];
    float*       out    = (float*)d_out;
    unsigned*    cs     = (unsigned*)d_ws;  // 10*512*4 = 20480 bytes

    const int ncs = BF_STAGES * (BF_DIM / 2);
    bf_fill_cs<<<(ncs + 255) / 256, 256, 0, stream>>>(angles, cs, ncs);

    const int rows    = in_sizes[0] / BF_DIM;
    const int n_pairs = (rows + 1) / 2;
    int blocks = (n_pairs + 3) / 4;
    if (blocks > 1024) blocks = 1024;     // 4 blocks/CU (40KB LDS) exactly resident
    const int pair_stride = blocks * 4;   // total waves
    bf_butterfly<<<blocks, 256, 0, stream>>>(x, (const f16x8*)cs, out, rows, pair_stride);
}

// Round 10
// 123.865 us; speedup vs baseline: 1.1854x; 1.0020x over previous
//
#include <hip/hip_runtime.h>
#include <hip/hip_fp16.h>

typedef float    f32x4 __attribute__((ext_vector_type(4)));
typedef _Float16 f16x8 __attribute__((ext_vector_type(8)));

#define BF_DIM 1024
#define BF_STAGES 10

// f16 (cos,sin) tables: 4 B/pair, 2 KB/stage, 20 KB total.
// Per stage, lane l's 8 needed pairs are packed contiguously at pairs [l*8..l*8+7]:
//   stages 0-3: pos = k (natural order IS lane-contiguous for the reg layout)
//   stages 4-7: k = hi2*128 + j*16 + lo4 -> pos = (hi2*16+lo4)*8 + j   (layout B)
//   stages 8-9: k = g*256 + lane*4 + c   -> pos = lane*8 + g*4 + c     (layout C)
__global__ void bf_fill_cs(const float* __restrict__ angles, unsigned* __restrict__ cs, int n) {
    int i = blockIdx.x * blockDim.x + threadIdx.x;
    if (i >= n) return;
    int s = i >> 9, k = i & 511;
    float a = angles[i];
    float sv, cv;
    sincosf(a, &sv, &cv);
    int pos;
    if (s >= 4 && s < 8) {
        int hi2 = k >> 7, j = (k >> 4) & 7, lo4 = k & 15;
        pos = ((hi2 << 4) | lo4) * 8 + j;
    } else if (s >= 8) {
        pos = ((k & 255) >> 2) * 8 + (k >> 8) * 4 + (k & 3);
    } else {
        pos = k;
    }
    unsigned hc = __half_as_ushort(__float2half_rn(cv));
    unsigned hs = __half_as_ushort(__float2half_rn(sv));
    cs[s * 512 + pos] = (hs << 16) | hc;   // low16 = cos, high16 = sin (LE)
}

#define ROT(vi, vj, c, s) do { float _t = fmaf(-(s), (vj), (c)*(vi)); \
                               (vj) = fmaf((s), (vi), (c)*(vj)); (vi) = _t; } while (0)

// Expand one f16x8 (4 cos/sin pairs) into two f32x4 coeff vecs (c0,s0,c1,s1).
#define EXP(t, ca, cb) do { \
    ca = (f32x4){(float)(t)[0], (float)(t)[1], (float)(t)[2], (float)(t)[3]}; \
    cb = (f32x4){(float)(t)[4], (float)(t)[5], (float)(t)[6], (float)(t)[7]}; } while (0)

// Half-stage ops on a pair of data vecs with 2 coeff vecs (4 pairs).
#define H_EVEN(P, Q, c0, c1) do { \
    ROT(P.x, P.y, c0.x, c0.y); ROT(P.z, P.w, c0.z, c0.w); \
    ROT(Q.x, Q.y, c1.x, c1.y); ROT(Q.z, Q.w, c1.z, c1.w); } while (0)
#define H_ODD(P, Q, c0, c1) do { \
    ROT(P.x, P.z, c0.x, c0.y); ROT(P.y, P.w, c0.z, c0.w); \
    ROT(Q.x, Q.z, c1.x, c1.y); ROT(Q.y, Q.w, c1.z, c1.w); } while (0)
#define H_PAIR(P, Q, c0, c1) do { \
    ROT(P.x, Q.x, c0.x, c0.y); ROT(P.y, Q.y, c0.z, c0.w); \
    ROT(P.z, Q.z, c1.x, c1.y); ROT(P.w, Q.w, c1.z, c1.w); } while (0)

// One full stage from two HOISTED f16x8 regs; expand lazily (t0 used on both
// rows, then t1 reuses the same coeff regs) to bound the transient live set.
#define DO_STAGE(HOP, t0, t1, X0, X1, X2, X3, Y0, Y1, Y2, Y3) do { \
    f32x4 _c0, _c1; \
    EXP(t0, _c0, _c1); \
    HOP(X0, X1, _c0, _c1); HOP(Y0, Y1, _c0, _c1); \
    EXP(t1, _c0, _c1); \
    HOP(X2, X3, _c0, _c1); HOP(Y2, Y3, _c0, _c1); } while (0)

// r9 structure (124us) + round-10 change: the ENTIRE per-lane table slice
// (20 x f16x8 = 80 VGPRs, loop-invariant) is hoisted into registers before
// the loop -> ZERO table VMEM in the loop body. __launch_bounds__(256,2)
// yields a 128-VGPR budget (round-2 evidence: it allocated exactly 128);
// live set = 32 data + 80 table + ~10 addressing ~ 122 < 128 -> no spill.
// Occupancy unchanged: 40 KB LDS already caps at 4 blocks/CU (16 waves/CU),
// so the bigger register footprint is free.
__global__ __launch_bounds__(256, 2) void bf_butterfly(const float* __restrict__ x,
                                                       const f16x8* __restrict__ TH,
                                                       float* __restrict__ out,
                                                       int n_rows, int pair_stride) {
    __shared__ __align__(16) float lds[4 * 2560];  // 4 waves * 2 rows * 20*64 words = 40 KB
    const int lane = threadIdx.x & 63;
    const int wv   = threadIdx.x >> 6;
    float* LA = lds + wv * 2560;   // row 0 slab
    float* LB = LA + 1280;         // row 1 slab

    const int wb = lane * 20;                         // layout A base
    const int rb = (lane >> 4) * 320 + (lane & 15);   // layout B base
    const int cb = (lane >> 2) * 20 + (lane & 3) * 4; // layout C base

    // ---- hoist all 10 stages' coefficients into registers (loop-invariant)
    const f16x8* tp = TH + lane * 2;
    f16x8 TA0 = tp[0 * 128], TB0 = tp[0 * 128 + 1];
    f16x8 TA1 = tp[1 * 128], TB1 = tp[1 * 128 + 1];
    f16x8 TA2 = tp[2 * 128], TB2 = tp[2 * 128 + 1];
    f16x8 TA3 = tp[3 * 128], TB3 = tp[3 * 128 + 1];
    f16x8 TA4 = tp[4 * 128], TB4 = tp[4 * 128 + 1];
    f16x8 TA5 = tp[5 * 128], TB5 = tp[5 * 128 + 1];
    f16x8 TA6 = tp[6 * 128], TB6 = tp[6 * 128 + 1];
    f16x8 TA7 = tp[7 * 128], TB7 = tp[7 * 128 + 1];
    f16x8 TA8 = tp[8 * 128], TB8 = tp[8 * 128 + 1];
    f16x8 TA9 = tp[9 * 128], TB9 = tp[9 * 128 + 1];

    const int n_pairs = (n_rows + 1) >> 1;

#pragma unroll 1
    for (int pair = blockIdx.x * 4 + wv; pair < n_pairs; pair += pair_stride) {
        const int r0 = pair * 2;
        const int r1 = r0 + 1;
        const bool has1 = (r1 < n_rows);

        const float* xr0 = x + (long long)r0 * BF_DIM + lane * 16;
        const float* xr1 = x + (long long)(has1 ? r1 : r0) * BF_DIM + lane * 16;
        f32x4 U0 = __builtin_nontemporal_load((const f32x4*)(xr0 + 0));
        f32x4 U1 = __builtin_nontemporal_load((const f32x4*)(xr0 + 4));
        f32x4 U2 = __builtin_nontemporal_load((const f32x4*)(xr0 + 8));
        f32x4 U3 = __builtin_nontemporal_load((const f32x4*)(xr0 + 12));
        f32x4 W0 = __builtin_nontemporal_load((const f32x4*)(xr1 + 0));
        f32x4 W1 = __builtin_nontemporal_load((const f32x4*)(xr1 + 4));
        f32x4 W2 = __builtin_nontemporal_load((const f32x4*)(xr1 + 8));
        f32x4 W3 = __builtin_nontemporal_load((const f32x4*)(xr1 + 12));

        // ---- stages 0-3 (layout A, in regs)
        DO_STAGE(H_EVEN, TA0, TB0, U0, U1, U2, U3, W0, W1, W2, W3);
        DO_STAGE(H_ODD,  TA1, TB1, U0, U1, U2, U3, W0, W1, W2, W3);
        DO_STAGE(H_PAIR, TA2, TB2, U0, U1, U2, U3, W0, W1, W2, W3);
        DO_STAGE(H_PAIR, TA3, TB3, U0, U2, U1, U3, W0, W2, W1, W3);  // pairs (0,2),(1,3)

        // ---- transpose 1: write layout A (b128), read layout B (b32); wave-private
        *(f32x4*)(LA + wb + 0)  = U0;
        *(f32x4*)(LA + wb + 4)  = U1;
        *(f32x4*)(LA + wb + 8)  = U2;
        *(f32x4*)(LA + wb + 12) = U3;
        *(f32x4*)(LB + wb + 0)  = W0;
        *(f32x4*)(LB + wb + 4)  = W1;
        *(f32x4*)(LB + wb + 8)  = W2;
        *(f32x4*)(LB + wb + 12) = W3;
        U0.x = LA[rb + 0 * 20];  U0.y = LA[rb + 1 * 20];  U0.z = LA[rb + 2 * 20];  U0.w = LA[rb + 3 * 20];
        U1.x = LA[rb + 4 * 20];  U1.y = LA[rb + 5 * 20];  U1.z = LA[rb + 6 * 20];  U1.w = LA[rb + 7 * 20];
        U2.x = LA[rb + 8 * 20];  U2.y = LA[rb + 9 * 20];  U2.z = LA[rb + 10 * 20]; U2.w = LA[rb + 11 * 20];
        U3.x = LA[rb + 12 * 20]; U3.y = LA[rb + 13 * 20]; U3.z = LA[rb + 14 * 20]; U3.w = LA[rb + 15 * 20];
        W0.x = LB[rb + 0 * 20];  W0.y = LB[rb + 1 * 20];  W0.z = LB[rb + 2 * 20];  W0.w = LB[rb + 3 * 20];
        W1.x = LB[rb + 4 * 20];  W1.y = LB[rb + 5 * 20];  W1.z = LB[rb + 6 * 20];  W1.w = LB[rb + 7 * 20];
        W2.x = LB[rb + 8 * 20];  W2.y = LB[rb + 9 * 20];  W2.z = LB[rb + 10 * 20]; W2.w = LB[rb + 11 * 20];
        W3.x = LB[rb + 12 * 20]; W3.y = LB[rb + 13 * 20]; W3.z = LB[rb + 14 * 20]; W3.w = LB[rb + 15 * 20];

        // ---- stages 4-7 (layout B, in regs)
        DO_STAGE(H_EVEN, TA4, TB4, U0, U1, U2, U3, W0, W1, W2, W3);
        DO_STAGE(H_ODD,  TA5, TB5, U0, U1, U2, U3, W0, W1, W2, W3);
        DO_STAGE(H_PAIR, TA6, TB6, U0, U1, U2, U3, W0, W1, W2, W3);
        DO_STAGE(H_PAIR, TA7, TB7, U0, U2, U1, U3, W0, W2, W1, W3);

        // ---- transpose 2: write layout B back (b32), read layout C (b128)
        LA[rb + 0 * 20]  = U0.x; LA[rb + 1 * 20]  = U0.y; LA[rb + 2 * 20]  = U0.z; LA[rb + 3 * 20]  = U0.w;
        LA[rb + 4 * 20]  = U1.x; LA[rb + 5 * 20]  = U1.y; LA[rb + 6 * 20]  = U1.z; LA[rb + 7 * 20]  = U1.w;
        LA[rb + 8 * 20]  = U2.x; LA[rb + 9 * 20]  = U2.y; LA[rb + 10 * 20] = U2.z; LA[rb + 11 * 20] = U2.w;
        LA[rb + 12 * 20] = U3.x; LA[rb + 13 * 20] = U3.y; LA[rb + 14 * 20] = U3.z; LA[rb + 15 * 20] = U3.w;
        LB[rb + 0 * 20]  = W0.x; LB[rb + 1 * 20]  = W0.y; LB[rb + 2 * 20]  = W0.z; LB[rb + 3 * 20]  = W0.w;
        LB[rb + 4 * 20]  = W1.x; LB[rb + 5 * 20]  = W1.y; LB[rb + 6 * 20]  = W1.z; LB[rb + 7 * 20]  = W1.w;
        LB[rb + 8 * 20]  = W2.x; LB[rb + 9 * 20]  = W2.y; LB[rb + 10 * 20] = W2.z; LB[rb + 11 * 20] = W2.w;
        LB[rb + 12 * 20] = W3.x; LB[rb + 13 * 20] = W3.y; LB[rb + 14 * 20] = W3.z; LB[rb + 15 * 20] = W3.w;
        U0 = *(const f32x4*)(LA + cb);
        U1 = *(const f32x4*)(LA + cb + 320);
        U2 = *(const f32x4*)(LA + cb + 640);
        U3 = *(const f32x4*)(LA + cb + 960);
        W0 = *(const f32x4*)(LB + cb);
        W1 = *(const f32x4*)(LB + cb + 320);
        W2 = *(const f32x4*)(LB + cb + 640);
        W3 = *(const f32x4*)(LB + cb + 960);

        // ---- stages 8-9 (layout C, in regs): (V0,V1),(V2,V3) then (V0,V2),(V1,V3)
        DO_STAGE(H_PAIR, TA8, TB8, U0, U1, U2, U3, W0, W1, W2, W3);
        DO_STAGE(H_PAIR, TA9, TB9, U0, U2, U1, U3, W0, W2, W1, W3);

        float* o0 = out + (long long)r0 * BF_DIM;
        __builtin_nontemporal_store(U0, (f32x4*)(o0 + lane * 4));
        __builtin_nontemporal_store(U1, (f32x4*)(o0 + 256 + lane * 4));
        __builtin_nontemporal_store(U2, (f32x4*)(o0 + 512 + lane * 4));
        __builtin_nontemporal_store(U3, (f32x4*)(o0 + 768 + lane * 4));
        if (has1) {
            float* o1 = out + (long long)r1 * BF_DIM;
            __builtin_nontemporal_store(W0, (f32x4*)(o1 + lane * 4));
            __builtin_nontemporal_store(W1, (f32x4*)(o1 + 256 + lane * 4));
            __builtin_nontemporal_store(W2, (f32x4*)(o1 + 512 + lane * 4));
            __builtin_nontemporal_store(W3, (f32x4*)(o1 + 768 + lane * 4));
        }
    }
}

extern "C" void kernel_launch(void* const* d_in, const int* in_sizes, int n_in,
                              void* d_out, int out_size, void* d_ws, size_t ws_size,
                              hipStream_t stream) {
    const float* x      = (const float*)d_in[0];
    const float* angles = (const float*)d_in[1];
    float*       out    = (float*)d_out;
    unsigned*    cs     = (unsigned*)d_ws;  // 10*512*4 = 20480 bytes

    const int ncs = BF_STAGES * (BF_DIM / 2);
    bf_fill_cs<<<(ncs + 255) / 256, 256, 0, stream>>>(angles, cs, ncs);

    const int rows    = in_sizes[0] / BF_DIM;
    const int n_pairs = (rows + 1) / 2;
    int blocks = (n_pairs + 3) / 4;
    if (blocks > 1024) blocks = 1024;     // 4 blocks/CU (40KB LDS) exactly resident
    const int pair_stride = blocks * 4;   // total waves
    bf_butterfly<<<blocks, 256, 0, stream>>>(x, (const f16x8*)cs, out, rows, pair_stride);
}